// Round 5
// baseline (122.077 us; speedup 1.0000x reference)
//
#include <hip/hip_runtime.h>

#define HH 1024
#define WW 1024
#define BB 8
#define WORDS_X 16             /* 64-px bit-words per row */

typedef unsigned long long u64;
typedef float f4 __attribute__((ext_vector_type(4)));   // builtin-compatible vec4

// ---------------------------------------------------------------------------
// Kernel 1: pack target (int32 0/1) into a bit image. Pure stream: per wave,
// 8 independent coalesced 256B loads -> 8 ballots -> one 64B store.
// The proven-fast reader (6.4 TB/s); do not touch.
// ---------------------------------------------------------------------------
__global__ __launch_bounds__(256) void ls_pack(const int* __restrict__ tgt,
                                               u64* __restrict__ bits) {
    const int lane = threadIdx.x & 63;
    const size_t wv = ((size_t)blockIdx.x * 256 + threadIdx.x) >> 6;
    const size_t wbase = wv * 8;                 // first of 8 words (512 px)
    const int* p = tgt + wbase * 64 + lane;

    int v[8];
#pragma unroll
    for (int j = 0; j < 8; ++j) v[j] = p[j * 64];

    u64 mine = 0;
#pragma unroll
    for (int j = 0; j < 8; ++j) {
        u64 m = __ballot(v[j] != 0);
        if (lane == j) mine = m;
    }
    if (lane < 8) bits[wbase + lane] = mine;
}

// ---------------------------------------------------------------------------
// Kernel 2: edge words from bit image (1MB -> 1MB, L2/L3-resident).
//   t_c=0: edge <=> OR of 11x11 window ; t_c=1: edge <=> !(AND of window)
// (exactly 121*t_c != window_sum with zero padding: OOB rows/words = 0.)
// ---------------------------------------------------------------------------
__global__ __launch_bounds__(256) void ls_edge(const u64* __restrict__ bits,
                                               u64* __restrict__ ebits) {
    __shared__ u64 s_b[26][17], s_oh[26][17], s_ah[26][17];  // +1 pad
    const int tid  = threadIdx.x;
    const int slab = blockIdx.x;      // 0..63
    const int b    = blockIdx.y;      // 0..7
    const int y0   = slab << 4;

#pragma unroll
    for (int i = tid; i < 416; i += 256) {
        int r = i >> 4, k = i & 15;
        int gy = y0 - 5 + r;
        u64 v = 0;
        if ((unsigned)gy < HH) v = bits[((size_t)(b << 10) + gy) * WORDS_X + k];
        s_b[r][k] = v;
    }
    __syncthreads();

#pragma unroll
    for (int i = tid; i < 416; i += 256) {
        int r = i >> 4, k = i & 15;
        u64 wm = s_b[r][k];
        u64 wl = k ? s_b[r][k - 1] : 0;
        u64 wr = (k < 15) ? s_b[r][k + 1] : 0;
        u64 oh = wm, ah = wm;
#pragma unroll
        for (int d = 1; d <= 5; ++d) {
            u64 vr = (wm >> d) | (wr << (64 - d));
            u64 vl = (wm << d) | (wl >> (64 - d));
            oh |= vr | vl;
            ah &= vr & vl;
        }
        s_oh[r][k] = oh;
        s_ah[r][k] = ah;
    }
    __syncthreads();

    {
        int r = tid >> 4, k = tid & 15;   // r: 0..15 within slab
        u64 ov = 0, av = ~0ULL;
#pragma unroll
        for (int j = 0; j < 11; ++j) { ov |= s_oh[r + j][k]; av &= s_ah[r + j][k]; }
        u64 tc = s_b[r + 5][k];
        ebits[((size_t)(b << 10) + y0 + r) * WORDS_X + k] = (ov & ~tc) | (~av & tc);
    }
}

// ---------------------------------------------------------------------------
// Kernel 3: streaming loss, PACK-SHAPED GEOMETRY.
// R3 lesson: 2048 long-lived blocks (8/CU, full-kernel lifetime, big VGPR
// in-flight set, reduction tail) stream at only ~2.2 TB/s with NO pipe
// saturated (HBM 25%, VALU 33%, occ 70%) -> block-structure/latency bound,
// not access-shape bound. ls_pack (4096 short blocks, few loads/thread,
// fast retire) reads at ~6.4 TB/s. This kernel copies that shape:
// 8192 one-row blocks; per thread: 1 float4/channel (1KB contiguous per
// wave-instr) + 2 broadcast mask words; minimal registers; quick retire.
// x loads are non-temporal (read-once; skip cache churn).
// NO device fences / cross-block atomics (r7/r8: __threadfence = ~88us L2
// storm; r10: contended f32 atomic = +12.7us tail).
// ---------------------------------------------------------------------------
__global__ __launch_bounds__(256) void ls_loss3(const float* __restrict__ x,
                                                const u64* __restrict__ bits,
                                                const u64* __restrict__ ebits,
                                                float* __restrict__ partial) {
    __shared__ float s_red[4];
    const int tid = threadIdx.x;
    const int R   = blockIdx.x;            // b*1024 + y
    const int b   = R >> 10;
    const int y   = R & 1023;

    const float* xr0 = x + ((size_t)b * 2) * (size_t)(HH * WW) + (size_t)y * WW;
    const f4 v0 = __builtin_nontemporal_load(((const f4*)xr0) + tid);
    const f4 v1 = __builtin_nontemporal_load(((const f4*)(xr0 + (size_t)HH * WW)) + tid);

    const size_t mrow = (size_t)R * WORDS_X + (tid >> 4);
    const u64 tw = bits[mrow];
    const u64 ew = ebits[mrow];
    const int sh = (tid & 15) << 2;        // bit pos of this 4-px nibble
    const unsigned t4 = (unsigned)(tw >> sh) & 0xfu;
    const unsigned e4 = (unsigned)(ew >> sh) & 0xfu;

    float acc = 0.f;
#pragma unroll
    for (int j = 0; j < 4; ++j) {
        int t = (t4 >> j) & 1;
        int e = (e4 >> j) & 1;
        float a0 = v0[j], a1 = v1[j];
        float m   = fmaxf(a0, a1);
        float lse = m + __logf(1.0f + __expf(-fabsf(a0 - a1)));
        float lp0 = a0 - lse, lp1 = a1 - lse;
        float lpt = t ? lp1 : lp0;
        float lpo = t ? lp0 : lp1;
        acc += e ? (0.95f * lpt + 0.1f * lpo) : lpt;
    }

#pragma unroll
    for (int off = 32; off > 0; off >>= 1) acc += __shfl_down(acc, off, 64);
    if ((tid & 63) == 0) s_red[tid >> 6] = acc;
    __syncthreads();
    if (tid == 0)
        partial[R] = s_red[0] + s_red[1] + s_red[2] + s_red[3];
}

__global__ __launch_bounds__(1024) void ls_final(const float* __restrict__ partial,
                                                 float* __restrict__ out) {
    __shared__ double s_red[16];
    const int tid = threadIdx.x;
    double s = 0.0;
#pragma unroll
    for (int k = 0; k < 8; ++k) s += (double)partial[tid + (k << 10)];
#pragma unroll
    for (int off = 32; off > 0; off >>= 1) s += __shfl_down(s, off, 64);
    if ((tid & 63) == 0) s_red[tid >> 6] = s;
    __syncthreads();
    if (tid == 0) {
        double total = 0.0;
#pragma unroll
        for (int i = 0; i < 16; ++i) total += s_red[i];
        out[0] = (float)(-total * (1.0 / (8.0 * 1024.0 * 1024.0)));
    }
}

extern "C" void kernel_launch(void* const* d_in, const int* in_sizes, int n_in,
                              void* d_out, int out_size, void* d_ws, size_t ws_size,
                              hipStream_t stream) {
    const float* x  = (const float*)d_in[0];
    const int* tgt  = (const int*)d_in[1];

    // ws: [partials 32KB][bits @64KB, 1MB][ebits @64KB+1MB, 1MB]
    float* partial = (float*)d_ws;
    u64* bits  = (u64*)((char*)d_ws + (64 << 10));
    u64* ebits = (u64*)((char*)d_ws + (64 << 10) + (1 << 20));

    hipLaunchKernelGGL(ls_pack, dim3(4096), dim3(256), 0, stream, tgt, bits);
    hipLaunchKernelGGL(ls_edge, dim3(64, 8), dim3(256), 0, stream, bits, ebits);
    hipLaunchKernelGGL(ls_loss3, dim3(8192), dim3(256), 0, stream, x, bits, ebits, partial);
    hipLaunchKernelGGL(ls_final, dim3(1), dim3(1024), 0, stream, partial, (float*)d_out);
}

// Round 6
// 119.178 us; speedup vs baseline: 1.0243x; 1.0243x over previous
//
#include <hip/hip_runtime.h>

#define HH 1024
#define WW 1024
#define BB 8
#define WORDS_X 16             /* 64-px bit-words per row */

typedef unsigned long long u64;
typedef float f4 __attribute__((ext_vector_type(4)));

// ---------------------------------------------------------------------------
// Kernel 1: pack target (int32 0/1) into a bit image. Per wave: 8 independent
// coalesced 256B loads -> 8 ballots -> one 64B store. Unchanged.
// ---------------------------------------------------------------------------
__global__ __launch_bounds__(256) void ls_pack(const int* __restrict__ tgt,
                                               u64* __restrict__ bits) {
    const int lane = threadIdx.x & 63;
    const size_t wv = ((size_t)blockIdx.x * 256 + threadIdx.x) >> 6;
    const size_t wbase = wv * 8;                 // first of 8 words (512 px)
    const int* p = tgt + wbase * 64 + lane;

    int v[8];
#pragma unroll
    for (int j = 0; j < 8; ++j) v[j] = p[j * 64];

    u64 mine = 0;
#pragma unroll
    for (int j = 0; j < 8; ++j) {
        u64 m = __ballot(v[j] != 0);
        if (lane == j) mine = m;
    }
    if (lane < 8) bits[wbase + lane] = mine;
}

// ---------------------------------------------------------------------------
// Kernel 2: edge words from bit image (1MB -> 1MB, L2/L3-resident).
//   t_c=0: edge <=> OR of 11x11 window ; t_c=1: edge <=> !(AND of window)
// (exactly 121*t_c != window_sum with zero padding: OOB rows/words = 0.)
// ---------------------------------------------------------------------------
__global__ __launch_bounds__(256) void ls_edge(const u64* __restrict__ bits,
                                               u64* __restrict__ ebits) {
    __shared__ u64 s_b[26][17], s_oh[26][17], s_ah[26][17];  // +1 pad
    const int tid  = threadIdx.x;
    const int slab = blockIdx.x;      // 0..63
    const int b    = blockIdx.y;      // 0..7
    const int y0   = slab << 4;

#pragma unroll
    for (int i = tid; i < 416; i += 256) {
        int r = i >> 4, k = i & 15;
        int gy = y0 - 5 + r;
        u64 v = 0;
        if ((unsigned)gy < HH) v = bits[((size_t)(b << 10) + gy) * WORDS_X + k];
        s_b[r][k] = v;
    }
    __syncthreads();

#pragma unroll
    for (int i = tid; i < 416; i += 256) {
        int r = i >> 4, k = i & 15;
        u64 wm = s_b[r][k];
        u64 wl = k ? s_b[r][k - 1] : 0;
        u64 wr = (k < 15) ? s_b[r][k + 1] : 0;
        u64 oh = wm, ah = wm;
#pragma unroll
        for (int d = 1; d <= 5; ++d) {
            u64 vr = (wm >> d) | (wr << (64 - d));
            u64 vl = (wm << d) | (wl >> (64 - d));
            oh |= vr | vl;
            ah &= vr & vl;
        }
        s_oh[r][k] = oh;
        s_ah[r][k] = ah;
    }
    __syncthreads();

    {
        int r = tid >> 4, k = tid & 15;   // r: 0..15 within slab
        u64 ov = 0, av = ~0ULL;
#pragma unroll
        for (int j = 0; j < 11; ++j) { ov |= s_oh[r + j][k]; av &= s_ah[r + j][k]; }
        u64 tc = s_b[r + 5][k];
        ebits[((size_t)(b << 10) + y0 + r) * WORDS_X + k] = (ov & ~tc) | (~av & tc);
    }
}

// ---------------------------------------------------------------------------
// Kernel 3: grid-strided SOFTWARE-PIPELINED loss.
// R5 lesson: block geometry (2048 tile vs 8192 row blocks) doesn't move the
// ~2.2 TB/s plateau. Common flaw of all prior variants: each thread issues
// its loads, waits vmcnt(0) on ALL of them, computes, retires -> no
// intra-thread overlap; only marginal in-flight bytes per CU. Here: 2048
// blocks (8/CU), each thread walks 4 chunks (row y of batches b0,b0+2,
// b0+4,b0+6 -- all strides compile-time const) with explicit prefetch:
// iter i+1's 2 float4 + 2 broadcast u64 loads are issued BEFORE iter i's
// math. ~4x in-flight bytes (~98KB/CU vs 21KB needed for 6.3TB/s), math
// covers HBM latency. Per-pixel math is BIT-IDENTICAL to the verified
// kernel; only summation order changes (proven safe in R2->R3, absmax 0.0).
// NO device fences / cross-block atomics (r7/r8/r10 lessons).
// ---------------------------------------------------------------------------
__global__ __launch_bounds__(256, 8) void ls_loss4(const float* __restrict__ x,
                                                   const u64* __restrict__ bits,
                                                   const u64* __restrict__ ebits,
                                                   float* __restrict__ partial) {
    __shared__ float s_red[4];
    const int tid = threadIdx.x;
    const int B   = blockIdx.x;          // 0..2047
    const int y   = B & 1023;
    const int b0  = B >> 10;             // 0 or 1
    // iteration it: row R = B + it*2048  ->  batch b = b0 + 2*it, same y.
    const f4* X = (const f4*)x;
    const size_t row4  = (size_t)b0 * 524288 + (size_t)y * 256 + tid; // ch0 f4 idx
    const size_t mbase = (size_t)B * WORDS_X + (tid >> 4);
    const int sh = (tid & 15) << 2;      // nibble position, const per thread

    f4 a0 = X[row4];                     // it=0, ch0
    f4 a1 = X[row4 + 262144];            // it=0, ch1
    u64 tw = bits[mbase];
    u64 ew = ebits[mbase];

    float acc = 0.f;
#pragma unroll
    for (int it = 0; it < 4; ++it) {
        f4 n0, n1; u64 ntw, netw;
        if (it < 3) {                    // prefetch next chunk (const strides)
            const size_t r4 = row4 + (size_t)(it + 1) * 1048576;
            n0 = X[r4];
            n1 = X[r4 + 262144];
            const size_t mb = mbase + (size_t)(it + 1) * 32768;
            ntw  = bits[mb];
            netw = ebits[mb];
        }
        const unsigned t4 = (unsigned)(tw >> sh) & 0xfu;
        const unsigned e4 = (unsigned)(ew >> sh) & 0xfu;
#pragma unroll
        for (int j = 0; j < 4; ++j) {
            int t = (t4 >> j) & 1;
            int e = (e4 >> j) & 1;
            float v0 = a0[j], v1 = a1[j];
            float m   = fmaxf(v0, v1);
            float lse = m + __logf(1.0f + __expf(-fabsf(v0 - v1)));
            float lp0 = v0 - lse, lp1 = v1 - lse;
            float lpt = t ? lp1 : lp0;
            float lpo = t ? lp0 : lp1;
            acc += e ? (0.95f * lpt + 0.1f * lpo) : lpt;
        }
        if (it < 3) { a0 = n0; a1 = n1; tw = ntw; ew = netw; }
    }

#pragma unroll
    for (int off = 32; off > 0; off >>= 1) acc += __shfl_down(acc, off, 64);
    if ((tid & 63) == 0) s_red[tid >> 6] = acc;
    __syncthreads();
    if (tid == 0)
        partial[B] = s_red[0] + s_red[1] + s_red[2] + s_red[3];
}

__global__ __launch_bounds__(1024) void ls_final(const float* __restrict__ partial,
                                                 float* __restrict__ out) {
    __shared__ double s_red[16];
    const int tid = threadIdx.x;
    double s = (double)partial[tid] + (double)partial[tid + 1024];
#pragma unroll
    for (int off = 32; off > 0; off >>= 1) s += __shfl_down(s, off, 64);
    if ((tid & 63) == 0) s_red[tid >> 6] = s;
    __syncthreads();
    if (tid == 0) {
        double total = 0.0;
#pragma unroll
        for (int i = 0; i < 16; ++i) total += s_red[i];
        out[0] = (float)(-total * (1.0 / (8.0 * 1024.0 * 1024.0)));
    }
}

extern "C" void kernel_launch(void* const* d_in, const int* in_sizes, int n_in,
                              void* d_out, int out_size, void* d_ws, size_t ws_size,
                              hipStream_t stream) {
    const float* x  = (const float*)d_in[0];
    const int* tgt  = (const int*)d_in[1];

    // ws: [partials 32KB][bits @64KB, 1MB][ebits @64KB+1MB, 1MB]
    float* partial = (float*)d_ws;
    u64* bits  = (u64*)((char*)d_ws + (64 << 10));
    u64* ebits = (u64*)((char*)d_ws + (64 << 10) + (1 << 20));

    hipLaunchKernelGGL(ls_pack, dim3(4096), dim3(256), 0, stream, tgt, bits);
    hipLaunchKernelGGL(ls_edge, dim3(64, 8), dim3(256), 0, stream, bits, ebits);
    hipLaunchKernelGGL(ls_loss4, dim3(2048), dim3(256), 0, stream, x, bits, ebits, partial);
    hipLaunchKernelGGL(ls_final, dim3(1), dim3(1024), 0, stream, partial, (float*)d_out);
}